// Round 1
// baseline (1434.403 us; speedup 1.0000x reference)
//
#include <hip/hip_runtime.h>
#include <math.h>

#define DEV __device__ __forceinline__

typedef __attribute__((ext_vector_type(8))) __bf16 bfrag;
typedef __attribute__((ext_vector_type(4))) float f4;
typedef __attribute__((ext_vector_type(8))) unsigned short u16x8;
typedef __attribute__((ext_vector_type(4))) unsigned short u16x4;

DEV unsigned short f2bf(float f) {
  unsigned u = __float_as_uint(f);
  u += 0x7fff + ((u >> 16) & 1);
  return (unsigned short)(u >> 16);
}

DEV void gload_lds16(const void* g, void* l) {
  __builtin_amdgcn_global_load_lds((const __attribute__((address_space(1))) void*)g,
                                   (__attribute__((address_space(3))) void*)l, 16, 0, 0);
}

// ---------------- GEMM: C[M,N] = A[M,K](bf16) * Bt[N,K](bf16)^T + bias (+epi) -------------
// EPI: 0 = bias only, 1 = bias+GELU(exact), 2 = bias+residual(f32)
// OUTBF: 1 = bf16 out, 0 = f32 out
template<int EPI, int OUTBF>
__global__ __launch_bounds__(256, 2)
void gemm_bt(const unsigned short* __restrict__ A,
             const unsigned short* __restrict__ Bt,
             const float* __restrict__ bias,
             const float* __restrict__ res,
             void* __restrict__ outp,
             int M, int N, int K)
{
  __shared__ unsigned short As[2][128 * 32];
  __shared__ unsigned short Bs[2][128 * 32];
  const int tid = threadIdx.x;
  const int lane = tid & 63;
  const int wid = tid >> 6;
  const int wr = wid >> 1, wc = wid & 1;
  const int l15 = lane & 15, lg = lane >> 4;
  const long tM = (long)blockIdx.x * 128;
  const long tN = (long)blockIdx.y * 128;

  const int c0 = tid, c1 = tid + 256;
  const int r0 = c0 >> 2, k0 = (c0 & 3) * 8;
  const int r1 = c1 >> 2, k1 = (c1 & 3) * 8;

  const unsigned short* A0 = A + (tM + r0) * (long)K + k0;
  const unsigned short* A1 = A + (tM + r1) * (long)K + k1;
  const unsigned short* B0 = Bt + (tN + r0) * (long)K + k0;
  const unsigned short* B1 = Bt + (tN + r1) * (long)K + k1;

  auto stage = [&](int kt, int buf) {
    const long ko = (long)kt * 32;
    gload_lds16(A0 + ko, &As[buf][c0 * 8]);
    gload_lds16(A1 + ko, &As[buf][c1 * 8]);
    gload_lds16(B0 + ko, &Bs[buf][c0 * 8]);
    gload_lds16(B1 + ko, &Bs[buf][c1 * 8]);
  };

  stage(0, 0);
  f4 acc[4][4] = {};
  const int nk = K >> 5;
  int cur = 0;
  __syncthreads();
  for (int kt = 0; kt < nk; ++kt) {
    if (kt + 1 < nk) stage(kt + 1, cur ^ 1);
    bfrag aF[4], bF[4];
#pragma unroll
    for (int m = 0; m < 4; ++m)
      aF[m] = *(const bfrag*)&As[cur][(wr * 64 + m * 16 + l15) * 32 + lg * 8];
#pragma unroll
    for (int n = 0; n < 4; ++n)
      bF[n] = *(const bfrag*)&Bs[cur][(wc * 64 + n * 16 + l15) * 32 + lg * 8];
#pragma unroll
    for (int m = 0; m < 4; ++m)
#pragma unroll
      for (int n = 0; n < 4; ++n)
        acc[m][n] = __builtin_amdgcn_mfma_f32_16x16x32_bf16(aF[m], bF[n], acc[m][n], 0, 0, 0);
    __syncthreads();
    cur ^= 1;
  }

#pragma unroll
  for (int m = 0; m < 4; ++m) {
#pragma unroll
    for (int n = 0; n < 4; ++n) {
      const long col = tN + wc * 64 + n * 16 + l15;
      const float bv = bias[col];
#pragma unroll
      for (int e = 0; e < 4; ++e) {
        const long row = tM + wr * 64 + m * 16 + lg * 4 + e;
        float v = acc[m][n][e] + bv;
        if (EPI == 1) v = 0.5f * v * (1.0f + erff(v * 0.70710678118654752f));
        if (EPI == 2) v += res[row * N + col];
        if (OUTBF) ((unsigned short*)outp)[row * N + col] = f2bf(v);
        else       ((float*)outp)[row * N + col] = v;
      }
    }
  }
}

// ---------------- LayerNorm (f32 in, bf16 out), one block per row of 3072 ----------------
__global__ __launch_bounds__(256)
void ln_bf16(const float* __restrict__ x, const float* __restrict__ g,
             const float* __restrict__ b, unsigned short* __restrict__ out)
{
  __shared__ float red[4];
  const int tid = threadIdx.x;
  const long row = blockIdx.x;
  const float* xr = x + row * 3072;
  float4 v[3];
  float s = 0.f;
#pragma unroll
  for (int i = 0; i < 3; ++i) {
    v[i] = *(const float4*)&xr[i * 1024 + tid * 4];
    s += v[i].x + v[i].y + v[i].z + v[i].w;
  }
#pragma unroll
  for (int o = 32; o > 0; o >>= 1) s += __shfl_xor(s, o);
  if ((tid & 63) == 0) red[tid >> 6] = s;
  __syncthreads();
  s = red[0] + red[1] + red[2] + red[3];
  const float mean = s * (1.f / 3072.f);
  float vs = 0.f;
#pragma unroll
  for (int i = 0; i < 3; ++i) {
    const float dx = v[i].x - mean, dy = v[i].y - mean;
    const float dz = v[i].z - mean, dw = v[i].w - mean;
    vs += dx * dx + dy * dy + dz * dz + dw * dw;
  }
#pragma unroll
  for (int o = 32; o > 0; o >>= 1) vs += __shfl_xor(vs, o);
  __syncthreads();
  if ((tid & 63) == 0) red[tid >> 6] = vs;
  __syncthreads();
  vs = red[0] + red[1] + red[2] + red[3];
  const float rstd = rsqrtf(vs * (1.f / 3072.f) + 1e-5f);
#pragma unroll
  for (int i = 0; i < 3; ++i) {
    const int idx = i * 1024 + tid * 4;
    const float* vp = (const float*)&v[i];
    u16x4 o4;
#pragma unroll
    for (int c = 0; c < 4; ++c)
      o4[c] = f2bf((vp[c] - mean) * rstd * g[idx + c] + b[idx + c]);
    *(u16x4*)&out[row * 3072 + idx] = o4;
  }
}

// ---------------- fp32 [R][C] -> bf16 [C][R] transpose-convert ----------------
__global__ __launch_bounds__(256)
void transpose_f32_bf16(const float* __restrict__ in, unsigned short* __restrict__ out,
                        int R, int C)
{
  __shared__ float tile[32][33];
  const int tx = threadIdx.x & 31, ty = threadIdx.x >> 5;
  const long r0 = (long)blockIdx.y * 32, cc0 = (long)blockIdx.x * 32;
#pragma unroll
  for (int i = 0; i < 4; ++i)
    tile[ty + 8 * i][tx] = in[(r0 + ty + 8 * i) * C + cc0 + tx];
  __syncthreads();
#pragma unroll
  for (int i = 0; i < 4; ++i)
    out[(cc0 + ty + 8 * i) * R + r0 + tx] = f2bf(tile[tx][ty + 8 * i]);
}

// ---------------- Flash attention fwd: q,k,v bf16 [B,S,H*96] -> ctx bf16 ----------------
// block = 256 thr (4 waves); per block: (b, h, 64 q-rows). KV tiles of 64.
// Swapped QK^T: S^T = mfma(Kfrag, Qfrag) so per-q reduction = shfl_xor(16,32).
__global__ __launch_bounds__(256, 2)
void attn_fwd(const unsigned short* __restrict__ qg,
              const unsigned short* __restrict__ kg,
              const unsigned short* __restrict__ vg,
              unsigned short* __restrict__ ctx)
{
  __shared__ unsigned short Qs[64 * 104];
  __shared__ unsigned short Ks[64 * 104];
  __shared__ unsigned short Vt[96 * 80];
  __shared__ unsigned short Ps[4 * 16 * 72];
  const int tid = threadIdx.x;
  const int lane = tid & 63;
  const int w = tid >> 6;
  const int l15 = lane & 15, lg = lane >> 4;
  const int bid = blockIdx.x;
  const int qb = bid & 31;
  const int h = (bid >> 5) & 31;
  const int b = bid >> 10;
  const long base = ((long)b * 2048) * 3072 + h * 96;
  const int qbase = qb * 64;

#pragma unroll
  for (int i = 0; i < 3; ++i) {
    const int c = tid + i * 256;
    const int r = c / 12, c8 = (c % 12) * 8;
    *(u16x8*)&Qs[r * 104 + c8] = *(const u16x8*)&qg[base + (long)(qbase + r) * 3072 + c8];
  }

  float m_run = -1e30f, l_run = 0.f;
  f4 O[6] = {};
  const float sc = 0.1020620726f * 1.4426950409f;  // 1/sqrt(96) * log2(e)

  for (int t = 0; t < 32; ++t) {
    __syncthreads();
    const int kb = t * 64;
#pragma unroll
    for (int i = 0; i < 3; ++i) {
      const int c = tid + i * 256;
      const int r = c / 12, c8 = (c % 12) * 8;
      *(u16x8*)&Ks[r * 104 + c8] = *(const u16x8*)&kg[base + (long)(kb + r) * 3072 + c8];
      const u16x8 vv = *(const u16x8*)&vg[base + (long)(kb + r) * 3072 + c8];
#pragma unroll
      for (int j = 0; j < 8; ++j)
        Vt[(c8 + j) * 80 + r] = vv[j];
    }
    __syncthreads();

    f4 sf[4];
#pragma unroll
    for (int mb = 0; mb < 4; ++mb) {
      f4 z = {0.f, 0.f, 0.f, 0.f};
      sf[mb] = z;
#pragma unroll
      for (int ks = 0; ks < 3; ++ks) {
        bfrag kf = *(const bfrag*)&Ks[(mb * 16 + l15) * 104 + ks * 32 + lg * 8];
        bfrag qf = *(const bfrag*)&Qs[(w * 16 + l15) * 104 + ks * 32 + lg * 8];
        sf[mb] = __builtin_amdgcn_mfma_f32_16x16x32_bf16(kf, qf, sf[mb], 0, 0, 0);
      }
    }
    float p[16];
    float tmax = -1e30f;
#pragma unroll
    for (int mb = 0; mb < 4; ++mb)
#pragma unroll
      for (int e = 0; e < 4; ++e) {
        const float sv = sf[mb][e] * sc;
        p[mb * 4 + e] = sv;
        tmax = fmaxf(tmax, sv);
      }
    tmax = fmaxf(tmax, __shfl_xor(tmax, 16));
    tmax = fmaxf(tmax, __shfl_xor(tmax, 32));
    const float mnew = fmaxf(m_run, tmax);
    const float alpha = exp2f(m_run - mnew);
    float psum = 0.f;
#pragma unroll
    for (int i = 0; i < 16; ++i) {
      p[i] = exp2f(p[i] - mnew);
      psum += p[i];
    }
    psum += __shfl_xor(psum, 16);
    psum += __shfl_xor(psum, 32);
    l_run = l_run * alpha + psum;
    m_run = mnew;
#pragma unroll
    for (int mb = 0; mb < 4; ++mb) {
      u16x4 pw;
#pragma unroll
      for (int e = 0; e < 4; ++e) pw[e] = f2bf(p[mb * 4 + e]);
      *(u16x4*)&Ps[w * 1152 + l15 * 72 + mb * 16 + lg * 4] = pw;
    }
    float aE[4];
#pragma unroll
    for (int e = 0; e < 4; ++e) aE[e] = __shfl(alpha, lg * 4 + e);
#pragma unroll
    for (int nb = 0; nb < 6; ++nb)
#pragma unroll
      for (int e = 0; e < 4; ++e) O[nb][e] *= aE[e];
#pragma unroll
    for (int nb = 0; nb < 6; ++nb)
#pragma unroll
      for (int ks = 0; ks < 2; ++ks) {
        bfrag pf = *(const bfrag*)&Ps[w * 1152 + l15 * 72 + ks * 32 + lg * 8];
        bfrag vf = *(const bfrag*)&Vt[(nb * 16 + l15) * 80 + ks * 32 + lg * 8];
        O[nb] = __builtin_amdgcn_mfma_f32_16x16x32_bf16(pf, vf, O[nb], 0, 0, 0);
      }
  }
  float lE[4];
#pragma unroll
  for (int e = 0; e < 4; ++e) lE[e] = 1.f / __shfl(l_run, lg * 4 + e);
#pragma unroll
  for (int nb = 0; nb < 6; ++nb)
#pragma unroll
    for (int e = 0; e < 4; ++e) {
      const long row = qbase + w * 16 + lg * 4 + e;
      ctx[base + row * 3072 + nb * 16 + l15] = f2bf(O[nb][e] * lE[e]);
    }
}

// ---------------- driver ----------------
extern "C" void kernel_launch(void* const* d_in, const int* in_sizes, int n_in,
                              void* d_out, int out_size, void* d_ws, size_t ws_size,
                              hipStream_t stream)
{
  (void)in_sizes; (void)n_in; (void)out_size; (void)ws_size;
  const float* x    = (const float*)d_in[0];
  const float* ln1g = (const float*)d_in[1];
  const float* ln1b = (const float*)d_in[2];
  const float* Wq   = (const float*)d_in[3];
  const float* bq   = (const float*)d_in[4];
  const float* Wk   = (const float*)d_in[5];
  const float* bk   = (const float*)d_in[6];
  const float* Wv   = (const float*)d_in[7];
  const float* bv   = (const float*)d_in[8];
  const float* Wo   = (const float*)d_in[9];
  const float* bo   = (const float*)d_in[10];
  const float* ln2g = (const float*)d_in[11];
  const float* ln2b = (const float*)d_in[12];
  const float* W1   = (const float*)d_in[13];
  const float* b1   = (const float*)d_in[14];
  const float* W2   = (const float*)d_in[15];
  const float* b2   = (const float*)d_in[16];

  char* ws = (char*)d_ws;
  // weight transposes (bf16 [N][K]), persistent for the call
  unsigned short* WqT = (unsigned short*)(ws + 0);
  unsigned short* WkT = (unsigned short*)(ws + 18874368);
  unsigned short* WvT = (unsigned short*)(ws + 37748736);
  unsigned short* WoT = (unsigned short*)(ws + 56623104);
  unsigned short* W1T = (unsigned short*)(ws + 75497472);
  unsigned short* W2T = (unsigned short*)(ws + 125829120);
  // activations (with lifetime-based reuse)
  unsigned short* hbf  = (unsigned short*)(ws + 176160768);  // LN1 out; later ctx
  unsigned short* ctxb = hbf;
  unsigned short* qb_  = (unsigned short*)(ws + 201326592);  // q; later h2
  unsigned short* h2   = qb_;
  unsigned short* kb_  = (unsigned short*)(ws + 226492416);  // k; later act (67 MB region)
  unsigned short* act  = kb_;
  unsigned short* vb_  = (unsigned short*)(ws + 293601280);  // v
  float*          h1   = (float*)(ws + 318767104);           // f32 residual

  const dim3 blk(256);

  transpose_f32_bf16<<<dim3(96, 96),  blk, 0, stream>>>(Wq, WqT, 3072, 3072);
  transpose_f32_bf16<<<dim3(96, 96),  blk, 0, stream>>>(Wk, WkT, 3072, 3072);
  transpose_f32_bf16<<<dim3(96, 96),  blk, 0, stream>>>(Wv, WvT, 3072, 3072);
  transpose_f32_bf16<<<dim3(96, 96),  blk, 0, stream>>>(Wo, WoT, 3072, 3072);
  transpose_f32_bf16<<<dim3(256, 96), blk, 0, stream>>>(W1, W1T, 3072, 8192);
  transpose_f32_bf16<<<dim3(96, 256), blk, 0, stream>>>(W2, W2T, 8192, 3072);

  ln_bf16<<<4096, blk, 0, stream>>>(x, ln1g, ln1b, hbf);

  gemm_bt<0, 1><<<dim3(32, 24), blk, 0, stream>>>(hbf, WqT, bq, nullptr, qb_, 4096, 3072, 3072);
  gemm_bt<0, 1><<<dim3(32, 24), blk, 0, stream>>>(hbf, WkT, bk, nullptr, kb_, 4096, 3072, 3072);
  gemm_bt<0, 1><<<dim3(32, 24), blk, 0, stream>>>(hbf, WvT, bv, nullptr, vb_, 4096, 3072, 3072);

  attn_fwd<<<2048, blk, 0, stream>>>(qb_, kb_, vb_, ctxb);

  gemm_bt<2, 0><<<dim3(32, 24), blk, 0, stream>>>(ctxb, WoT, bo, x, h1, 4096, 3072, 3072);

  ln_bf16<<<4096, blk, 0, stream>>>(h1, ln2g, ln2b, h2);

  gemm_bt<1, 1><<<dim3(32, 64), blk, 0, stream>>>(h2, W1T, b1, nullptr, act, 4096, 8192, 3072);
  gemm_bt<2, 0><<<dim3(32, 24), blk, 0, stream>>>(act, W2T, b2, h1, (float*)d_out, 4096, 3072, 8192);
}

// Round 2
// 1250.095 us; speedup vs baseline: 1.1474x; 1.1474x over previous
//
#include <hip/hip_runtime.h>
#include <math.h>

#define DEV __device__ __forceinline__

typedef __attribute__((ext_vector_type(8))) __bf16 bfrag;
typedef __attribute__((ext_vector_type(4))) float f4;
typedef __attribute__((ext_vector_type(8))) unsigned short u16x8;
typedef __attribute__((ext_vector_type(4))) unsigned short u16x4;

DEV unsigned short f2bf(float f) {
  unsigned u = __float_as_uint(f);
  u += 0x7fff + ((u >> 16) & 1);
  return (unsigned short)(u >> 16);
}

DEV void gload_lds16(const void* g, void* l) {
  __builtin_amdgcn_global_load_lds((const __attribute__((address_space(1))) void*)g,
                                   (__attribute__((address_space(3))) void*)l, 16, 0, 0);
}

// ---------------- GEMM: C[M,N] = A[M,K](bf16) * Bt[N,K](bf16)^T + bias (+epi) -------------
// EPI: 0 = bias only, 1 = bias+GELU(exact), 2 = bias+residual(f32)
// OUTBF: 1 = bf16 out, 0 = f32 out
// BIASROW: 0 = bias[col], 1 = bias[row]
template<int EPI, int OUTBF, int BIASROW>
__global__ __launch_bounds__(256, 2)
void gemm_bt(const unsigned short* __restrict__ A,
             const unsigned short* __restrict__ Bt,
             const float* __restrict__ bias,
             const float* __restrict__ res,
             void* __restrict__ outp,
             int M, int N, int K)
{
  __shared__ unsigned short As[2][128 * 32];
  __shared__ unsigned short Bs[2][128 * 32];
  const int tid = threadIdx.x;
  const int lane = tid & 63;
  const int wid = tid >> 6;
  const int wr = wid >> 1, wc = wid & 1;
  const int l15 = lane & 15, lg = lane >> 4;
  const long tM = (long)blockIdx.x * 128;
  const long tN = (long)blockIdx.y * 128;

  const int c0 = tid, c1 = tid + 256;
  const int r0 = c0 >> 2, k0 = (c0 & 3) * 8;
  const int r1 = c1 >> 2, k1 = (c1 & 3) * 8;

  const unsigned short* A0 = A + (tM + r0) * (long)K + k0;
  const unsigned short* A1 = A + (tM + r1) * (long)K + k1;
  const unsigned short* B0 = Bt + (tN + r0) * (long)K + k0;
  const unsigned short* B1 = Bt + (tN + r1) * (long)K + k1;

  auto stage = [&](int kt, int buf) {
    const long ko = (long)kt * 32;
    gload_lds16(A0 + ko, &As[buf][c0 * 8]);
    gload_lds16(A1 + ko, &As[buf][c1 * 8]);
    gload_lds16(B0 + ko, &Bs[buf][c0 * 8]);
    gload_lds16(B1 + ko, &Bs[buf][c1 * 8]);
  };

  stage(0, 0);
  f4 acc[4][4] = {};
  const int nk = K >> 5;
  int cur = 0;
  __syncthreads();
  for (int kt = 0; kt < nk; ++kt) {
    if (kt + 1 < nk) stage(kt + 1, cur ^ 1);
    bfrag aF[4], bF[4];
#pragma unroll
    for (int m = 0; m < 4; ++m)
      aF[m] = *(const bfrag*)&As[cur][(wr * 64 + m * 16 + l15) * 32 + lg * 8];
#pragma unroll
    for (int n = 0; n < 4; ++n)
      bF[n] = *(const bfrag*)&Bs[cur][(wc * 64 + n * 16 + l15) * 32 + lg * 8];
#pragma unroll
    for (int m = 0; m < 4; ++m)
#pragma unroll
      for (int n = 0; n < 4; ++n)
        acc[m][n] = __builtin_amdgcn_mfma_f32_16x16x32_bf16(aF[m], bF[n], acc[m][n], 0, 0, 0);
    __syncthreads();
    cur ^= 1;
  }

#pragma unroll
  for (int m = 0; m < 4; ++m) {
#pragma unroll
    for (int n = 0; n < 4; ++n) {
      const long col = tN + wc * 64 + n * 16 + l15;
      const float bcol = BIASROW ? 0.f : bias[col];
#pragma unroll
      for (int e = 0; e < 4; ++e) {
        const long row = tM + wr * 64 + m * 16 + lg * 4 + e;
        float v = acc[m][n][e] + (BIASROW ? bias[row] : bcol);
        if (EPI == 1) v = 0.5f * v * (1.0f + erff(v * 0.70710678118654752f));
        if (EPI == 2) v += res[row * N + col];
        if (OUTBF) ((unsigned short*)outp)[row * N + col] = f2bf(v);
        else       ((float*)outp)[row * N + col] = v;
      }
    }
  }
}

// ---------------- LayerNorm (f32 in, bf16 out), one block per row of 3072 ----------------
__global__ __launch_bounds__(256)
void ln_bf16(const float* __restrict__ x, const float* __restrict__ g,
             const float* __restrict__ b, unsigned short* __restrict__ out)
{
  __shared__ float red[4];
  const int tid = threadIdx.x;
  const long row = blockIdx.x;
  const float* xr = x + row * 3072;
  float4 v[3];
  float s = 0.f;
#pragma unroll
  for (int i = 0; i < 3; ++i) {
    v[i] = *(const float4*)&xr[i * 1024 + tid * 4];
    s += v[i].x + v[i].y + v[i].z + v[i].w;
  }
#pragma unroll
  for (int o = 32; o > 0; o >>= 1) s += __shfl_xor(s, o);
  if ((tid & 63) == 0) red[tid >> 6] = s;
  __syncthreads();
  s = red[0] + red[1] + red[2] + red[3];
  const float mean = s * (1.f / 3072.f);
  float vs = 0.f;
#pragma unroll
  for (int i = 0; i < 3; ++i) {
    const float dx = v[i].x - mean, dy = v[i].y - mean;
    const float dz = v[i].z - mean, dw = v[i].w - mean;
    vs += dx * dx + dy * dy + dz * dz + dw * dw;
  }
#pragma unroll
  for (int o = 32; o > 0; o >>= 1) vs += __shfl_xor(vs, o);
  __syncthreads();
  if ((tid & 63) == 0) red[tid >> 6] = vs;
  __syncthreads();
  vs = red[0] + red[1] + red[2] + red[3];
  const float rstd = rsqrtf(vs * (1.f / 3072.f) + 1e-5f);
#pragma unroll
  for (int i = 0; i < 3; ++i) {
    const int idx = i * 1024 + tid * 4;
    const float* vp = (const float*)&v[i];
    u16x4 o4;
#pragma unroll
    for (int c = 0; c < 4; ++c)
      o4[c] = f2bf((vp[c] - mean) * rstd * g[idx + c] + b[idx + c]);
    *(u16x4*)&out[row * 3072 + idx] = o4;
  }
}

// ---------------- fp32 [R][C] -> bf16 [C][R] transpose-convert ----------------
__global__ __launch_bounds__(256)
void transpose_f32_bf16(const float* __restrict__ in, unsigned short* __restrict__ out,
                        int R, int C)
{
  __shared__ float tile[32][33];
  const int tx = threadIdx.x & 31, ty = threadIdx.x >> 5;
  const long r0 = (long)blockIdx.y * 32, cc0 = (long)blockIdx.x * 32;
#pragma unroll
  for (int i = 0; i < 4; ++i)
    tile[ty + 8 * i][tx] = in[(r0 + ty + 8 * i) * C + cc0 + tx];
  __syncthreads();
#pragma unroll
  for (int i = 0; i < 4; ++i)
    out[(cc0 + ty + 8 * i) * R + r0 + tx] = f2bf(tile[tx][ty + 8 * i]);
}

// ---------------- Flash attention fwd ----------------
// q,k bf16 [B,S,H*96]; vT bf16 [H*96][B*S]; ctx bf16 [B,S,H*96]
// block = 256 thr (4 waves); per block: (b, h, 64 q-rows). KV tiles of 64.
// Swapped QK^T: S^T = mfma(Kfrag, Qfrag) so per-q reduction = shfl_xor(16,32).
__global__ __launch_bounds__(256, 3)
void attn_fwd(const unsigned short* __restrict__ qg,
              const unsigned short* __restrict__ kg,
              const unsigned short* __restrict__ vT,
              unsigned short* __restrict__ ctx)
{
  __shared__ unsigned short Qs[64 * 104];
  __shared__ unsigned short Ks[64 * 104];
  __shared__ unsigned short Vt[96 * 72];
  __shared__ unsigned short Ps[4 * 16 * 72];
  const int tid = threadIdx.x;
  const int lane = tid & 63;
  const int w = tid >> 6;
  const int l15 = lane & 15, lg = lane >> 4;
  // XCD-aware swizzle: all 32 q-blocks of one (b,h) land on one XCD's L2
  const int bid = (blockIdx.x & 7) * 256 + (blockIdx.x >> 3);
  const int qb = bid & 31;
  const int h = (bid >> 5) & 31;
  const int b = bid >> 10;
  const long base = ((long)b * 2048) * 3072 + h * 96;
  const long vbase = (long)(h * 96) * 4096 + (long)b * 2048;
  const int qbase = qb * 64;

#pragma unroll
  for (int i = 0; i < 3; ++i) {
    const int c = tid + i * 256;
    const int r = c / 12, c8 = (c % 12) * 8;
    *(u16x8*)&Qs[r * 104 + c8] = *(const u16x8*)&qg[base + (long)(qbase + r) * 3072 + c8];
  }

  float m_run = -1e30f, l_run = 0.f;
  f4 O[6] = {};
  const float sc = 0.1020620726f * 1.4426950409f;  // 1/sqrt(96) * log2(e)

  for (int t = 0; t < 32; ++t) {
    __syncthreads();
    const int kb = t * 64;
    // K tile [64 kv][96 d], padded stride 104
#pragma unroll
    for (int i = 0; i < 3; ++i) {
      const int c = tid + i * 256;
      const int r = c / 12, c8 = (c % 12) * 8;
      *(u16x8*)&Ks[r * 104 + c8] = *(const u16x8*)&kg[base + (long)(kb + r) * 3072 + c8];
    }
    // V^T tile [96 d][64 kv], padded stride 72, straight from global (no transpose)
#pragma unroll
    for (int i = 0; i < 3; ++i) {
      const int idx = tid + i * 256;
      const int d = idx >> 3, c8 = (idx & 7) * 8;
      *(u16x8*)&Vt[d * 72 + c8] = *(const u16x8*)&vT[vbase + (long)d * 4096 + kb + c8];
    }
    __syncthreads();

    f4 sf[4];
#pragma unroll
    for (int mb = 0; mb < 4; ++mb) {
      f4 z = {0.f, 0.f, 0.f, 0.f};
      sf[mb] = z;
#pragma unroll
      for (int ks = 0; ks < 3; ++ks) {
        bfrag kf = *(const bfrag*)&Ks[(mb * 16 + l15) * 104 + ks * 32 + lg * 8];
        bfrag qf = *(const bfrag*)&Qs[(w * 16 + l15) * 104 + ks * 32 + lg * 8];
        sf[mb] = __builtin_amdgcn_mfma_f32_16x16x32_bf16(kf, qf, sf[mb], 0, 0, 0);
      }
    }
    float p[16];
    float tmax = -1e30f;
#pragma unroll
    for (int mb = 0; mb < 4; ++mb)
#pragma unroll
      for (int e = 0; e < 4; ++e) {
        const float sv = sf[mb][e] * sc;
        p[mb * 4 + e] = sv;
        tmax = fmaxf(tmax, sv);
      }
    tmax = fmaxf(tmax, __shfl_xor(tmax, 16));
    tmax = fmaxf(tmax, __shfl_xor(tmax, 32));
    const float mnew = fmaxf(m_run, tmax);
    const float alpha = exp2f(m_run - mnew);
    float psum = 0.f;
#pragma unroll
    for (int i = 0; i < 16; ++i) {
      p[i] = exp2f(p[i] - mnew);
      psum += p[i];
    }
    psum += __shfl_xor(psum, 16);
    psum += __shfl_xor(psum, 32);
    l_run = l_run * alpha + psum;
    m_run = mnew;
#pragma unroll
    for (int mb = 0; mb < 4; ++mb) {
      u16x4 pw;
#pragma unroll
      for (int e = 0; e < 4; ++e) pw[e] = f2bf(p[mb * 4 + e]);
      *(u16x4*)&Ps[w * 1152 + l15 * 72 + mb * 16 + lg * 4] = pw;
    }
    float aE[4];
#pragma unroll
    for (int e = 0; e < 4; ++e) aE[e] = __shfl(alpha, lg * 4 + e);
#pragma unroll
    for (int nb = 0; nb < 6; ++nb)
#pragma unroll
      for (int e = 0; e < 4; ++e) O[nb][e] *= aE[e];
#pragma unroll
    for (int nb = 0; nb < 6; ++nb)
#pragma unroll
      for (int ks = 0; ks < 2; ++ks) {
        bfrag pf = *(const bfrag*)&Ps[w * 1152 + l15 * 72 + ks * 32 + lg * 8];
        bfrag vf = *(const bfrag*)&Vt[(nb * 16 + l15) * 72 + ks * 32 + lg * 8];
        O[nb] = __builtin_amdgcn_mfma_f32_16x16x32_bf16(pf, vf, O[nb], 0, 0, 0);
      }
  }
  float lE[4];
#pragma unroll
  for (int e = 0; e < 4; ++e) lE[e] = 1.f / __shfl(l_run, lg * 4 + e);
#pragma unroll
  for (int nb = 0; nb < 6; ++nb)
#pragma unroll
    for (int e = 0; e < 4; ++e) {
      const long row = qbase + w * 16 + lg * 4 + e;
      ctx[base + row * 3072 + nb * 16 + l15] = f2bf(O[nb][e] * lE[e]);
    }
}

// ---------------- driver ----------------
extern "C" void kernel_launch(void* const* d_in, const int* in_sizes, int n_in,
                              void* d_out, int out_size, void* d_ws, size_t ws_size,
                              hipStream_t stream)
{
  (void)in_sizes; (void)n_in; (void)out_size; (void)ws_size;
  const float* x    = (const float*)d_in[0];
  const float* ln1g = (const float*)d_in[1];
  const float* ln1b = (const float*)d_in[2];
  const float* Wq   = (const float*)d_in[3];
  const float* bq   = (const float*)d_in[4];
  const float* Wk   = (const float*)d_in[5];
  const float* bk   = (const float*)d_in[6];
  const float* Wv   = (const float*)d_in[7];
  const float* bv   = (const float*)d_in[8];
  const float* Wo   = (const float*)d_in[9];
  const float* bo   = (const float*)d_in[10];
  const float* ln2g = (const float*)d_in[11];
  const float* ln2b = (const float*)d_in[12];
  const float* W1   = (const float*)d_in[13];
  const float* b1   = (const float*)d_in[14];
  const float* W2   = (const float*)d_in[15];
  const float* b2   = (const float*)d_in[16];

  char* ws = (char*)d_ws;
  // weight transposes (bf16 [N][K]), persistent for the call
  unsigned short* WqT = (unsigned short*)(ws + 0);
  unsigned short* WkT = (unsigned short*)(ws + 18874368);
  unsigned short* WvT = (unsigned short*)(ws + 37748736);
  unsigned short* WoT = (unsigned short*)(ws + 56623104);
  unsigned short* W1T = (unsigned short*)(ws + 75497472);
  unsigned short* W2T = (unsigned short*)(ws + 125829120);
  // activations (with lifetime-based reuse)
  unsigned short* hbf  = (unsigned short*)(ws + 176160768);  // LN1 out; later ctx
  unsigned short* ctxb = hbf;
  unsigned short* qb_  = (unsigned short*)(ws + 201326592);  // q; later h2
  unsigned short* h2   = qb_;
  unsigned short* kb_  = (unsigned short*)(ws + 226492416);  // k; later act (67 MB region)
  unsigned short* act  = kb_;
  unsigned short* vb_  = (unsigned short*)(ws + 293601280);  // vT [3072][4096]
  float*          h1   = (float*)(ws + 318767104);           // f32 residual

  const dim3 blk(256);

  transpose_f32_bf16<<<dim3(96, 96),  blk, 0, stream>>>(Wq, WqT, 3072, 3072);
  transpose_f32_bf16<<<dim3(96, 96),  blk, 0, stream>>>(Wk, WkT, 3072, 3072);
  transpose_f32_bf16<<<dim3(96, 96),  blk, 0, stream>>>(Wv, WvT, 3072, 3072);
  transpose_f32_bf16<<<dim3(96, 96),  blk, 0, stream>>>(Wo, WoT, 3072, 3072);
  transpose_f32_bf16<<<dim3(256, 96), blk, 0, stream>>>(W1, W1T, 3072, 8192);
  transpose_f32_bf16<<<dim3(96, 256), blk, 0, stream>>>(W2, W2T, 8192, 3072);

  ln_bf16<<<4096, blk, 0, stream>>>(x, ln1g, ln1b, hbf);

  gemm_bt<0, 1, 0><<<dim3(32, 24), blk, 0, stream>>>(hbf, WqT, bq, nullptr, qb_, 4096, 3072, 3072);
  gemm_bt<0, 1, 0><<<dim3(32, 24), blk, 0, stream>>>(hbf, WkT, bk, nullptr, kb_, 4096, 3072, 3072);
  // V projection with swapped operands -> output is vT [3072][4096] (bias is per-row)
  gemm_bt<0, 1, 1><<<dim3(24, 32), blk, 0, stream>>>(WvT, hbf, bv, nullptr, vb_, 3072, 4096, 3072);

  attn_fwd<<<2048, blk, 0, stream>>>(qb_, kb_, vb_, ctxb);

  gemm_bt<2, 0, 0><<<dim3(32, 24), blk, 0, stream>>>(ctxb, WoT, bo, x, h1, 4096, 3072, 3072);

  ln_bf16<<<4096, blk, 0, stream>>>(h1, ln2g, ln2b, h2);

  gemm_bt<1, 1, 0><<<dim3(32, 64), blk, 0, stream>>>(h2, W1T, b1, nullptr, act, 4096, 8192, 3072);
  gemm_bt<2, 0, 0><<<dim3(32, 24), blk, 0, stream>>>(act, W2T, b2, h1, (float*)d_out, 4096, 3072, 8192);
}